// Round 4
// baseline (2843.065 us; speedup 1.0000x reference)
//
#include <hip/hip_runtime.h>

typedef unsigned int u32;
typedef unsigned short u16;
using u32x4 = __attribute__((ext_vector_type(4))) u32;
using f16x8 = __attribute__((ext_vector_type(8))) _Float16;
using f32x4 = __attribute__((ext_vector_type(4))) float;

#define LT 512
#define BNB 64
#define ED 512
#define HD 1024
#define OUT_HALF_BYTES ((size_t)LT * BNB * HD * 4)  // 134217728 bytes per output tensor

// workspace layout (bytes)
#define WXP_OFF  ((size_t)0)                         // 4 MB  f16 fragment-packed Wx
#define WHP_OFF  ((size_t)(4u << 20))                // 8 MB  f16 fragment-packed Wh
#define BIAS_OFF ((size_t)(12u << 20))               // 16 KB packed bias (f32)
#define HSTG_OFF ((size_t)((12u << 20) + (16u << 10)))  // 512 KB tagged h ping-pong (u32)

__device__ __forceinline__ u16 f2h(float f) {
  _Float16 h = (_Float16)f;
  return __builtin_bit_cast(u16, h);
}
__device__ __forceinline__ float h2f(u16 s) {
  return (float)__builtin_bit_cast(_Float16, s);
}
__device__ __forceinline__ u32 pk2(float a, float b) {
  return (u32)f2h(a) | ((u32)f2h(b) << 16);
}
__device__ __forceinline__ void glds16(const void* g, void* l) {
  using GP = const __attribute__((address_space(1))) u32*;
  using SP = __attribute__((address_space(3))) u32*;
  __builtin_amdgcn_global_load_lds((GP)g, (SP)l, 16, 0, 0);
}
__device__ __forceinline__ f32x4 mfma_f16(f16x8 a, f16x8 b, f32x4 c) {
  return __builtin_amdgcn_mfma_f32_16x16x32_f16(a, b, c, 0, 0, 0);
}
__device__ __forceinline__ float sigm(float x) { return 1.0f / (1.0f + __expf(-x)); }
__device__ __forceinline__ float tanh_(float x) { return 2.0f / (1.0f + __expf(-2.0f * x)) - 1.0f; }

// ---- coherent (LLC-level, cross-XCD) ops: bypass L1+L2 with sc0 sc1 ----
__device__ __forceinline__ u32x4 ldg16_cc(const void* p) {
  u32x4 r;
  asm volatile("global_load_dwordx4 %0, %1, off sc0 sc1" : "=v"(r) : "v"(p) : "memory");
  return r;
}
__device__ __forceinline__ void stg_u32_cc(void* p, u32 v) {
  asm volatile("global_store_dword %0, %1, off sc0 sc1" ::"v"(p), "v"(v) : "memory");
}
__device__ __forceinline__ u32 ldg_u16_plain(const void* p) {
  u32 r;
  asm volatile("global_load_ushort %0, %1, off" : "=v"(r) : "v"(p) : "memory");
  return r;
}
__device__ __forceinline__ void waitv0() { asm volatile("s_waitcnt vmcnt(0)" ::: "memory"); }

// unpack 8 tagged dwords (low16 = f16) into an f16x8 A-fragment
__device__ __forceinline__ f16x8 unpk(u32x4 lo, u32x4 hi) {
  u32x4 w;
  w[0] = (lo[0] & 0xFFFFu) | (lo[1] << 16);
  w[1] = (lo[2] & 0xFFFFu) | (lo[3] << 16);
  w[2] = (hi[0] & 0xFFFFu) | (hi[1] << 16);
  w[3] = (hi[2] & 0xFFFFu) | (hi[3] << 16);
  return __builtin_bit_cast(f16x8, w);
}

// ---------------- weight packing ----------------
// fragment convention for mfma_f32_16x16x32: lane l holds
//   A[row=l&15][k=8*(l>>4)+i]   B[k=8*(l>>4)+i][col=l&15]   (i=0..7, 16B per lane)
// gate-interleaved column index: n' = cg*64 + g*16 + j  (cg=0..63, g=f/i/g/o, j=0..15)

__global__ void pack_wx(const float* __restrict__ Wf, const float* __restrict__ Wi,
                        const float* __restrict__ Wg, const float* __restrict__ Wo,
                        u32x4* __restrict__ dst) {
  const int id = blockIdx.x * 256 + threadIdx.x;  // 262144 = 4096 frag-rows * 64 lanes
  const int lane = id & 63;
  const int row = id >> 6;           // ((ntile*16 + kt)*8 + fn)
  const int ntile = row >> 7;
  const int rem = row & 127;
  const int kt = rem >> 3;
  const int fn = rem & 7;
  const int np = (ntile << 7) + (fn << 4) + (lane & 15);
  const int g = (np >> 4) & 3;
  const int jfull = ((np >> 6) << 4) + (np & 15);
  const int k0 = (kt << 5) + ((lane >> 4) << 3);
  const float* W = (g == 0) ? Wf : (g == 1) ? Wi : (g == 2) ? Wg : Wo;
  const float* s = W + (size_t)k0 * HD + jfull;
  u16 h[8];
#pragma unroll
  for (int i = 0; i < 8; ++i) h[i] = f2h(s[(size_t)i * HD]);
  u32x4 v;
  v[0] = (u32)h[0] | ((u32)h[1] << 16);
  v[1] = (u32)h[2] | ((u32)h[3] << 16);
  v[2] = (u32)h[4] | ((u32)h[5] << 16);
  v[3] = (u32)h[6] | ((u32)h[7] << 16);
  dst[id] = v;
}

// Wh layout (r2-proven): frag-row = ((cg*4 + w)*4 + g)*8 + kk
__global__ void pack_wh(const float* __restrict__ Wf, const float* __restrict__ Wi,
                        const float* __restrict__ Wg, const float* __restrict__ Wo,
                        u32x4* __restrict__ dst) {
  const int id = blockIdx.x * 256 + threadIdx.x;  // 524288 = 8192 frag-rows * 64 lanes
  const int lane = id & 63;
  const int row = id >> 6;           // ((cg*4 + w)*4 + g)*8 + kk
  const int cg = row >> 7;
  const int rem = row & 127;
  const int w = rem >> 5;
  const int g = (rem >> 3) & 3;
  const int kk = rem & 7;
  const int k = ED + (w << 8) + (kk << 5) + ((lane >> 4) << 3);  // h-part rows of W
  const int j = (cg << 4) + (lane & 15);
  const float* W = (g == 0) ? Wf : (g == 1) ? Wi : (g == 2) ? Wg : Wo;
  const float* s = W + (size_t)k * HD + j;
  u16 h[8];
#pragma unroll
  for (int i = 0; i < 8; ++i) h[i] = f2h(s[(size_t)i * HD]);
  u32x4 v;
  v[0] = (u32)h[0] | ((u32)h[1] << 16);
  v[1] = (u32)h[2] | ((u32)h[3] << 16);
  v[2] = (u32)h[4] | ((u32)h[5] << 16);
  v[3] = (u32)h[6] | ((u32)h[7] << 16);
  dst[id] = v;
}

__global__ void pack_bias(const float* __restrict__ bf, const float* __restrict__ bi,
                          const float* __restrict__ bg, const float* __restrict__ bo,
                          float* __restrict__ dst) {
  const int id = blockIdx.x * 256 + threadIdx.x;  // 4096
  const int g = (id >> 4) & 3;
  const int jfull = ((id >> 6) << 4) + (id & 15);
  const float* B = (g == 0) ? bf : (g == 1) ? bi : (g == 2) ? bg : bo;
  dst[id] = B[jfull];
}

// ---------------- zx = X @ Wx + b  (written f16 into d_out's own bytes) ----------------
// zx element (m=t*64+b, n'=cg*64+g*16+j) lives at:
//   (g<2 ? c_half : h_half) + m*4096 + cg*64 + (g&1)*32 + j*2
// i.e. exactly the bytes that step t of the recurrence later overwrites with c/h.

__global__ __launch_bounds__(256) void zx_gemm(const float* __restrict__ x,
                                               const u32x4* __restrict__ wxp,
                                               const float* __restrict__ biasp,
                                               char* __restrict__ outb) {
  __shared__ u32x4 Ab[512];  // 8 KB  [fm 0..7][lane][16B]
  __shared__ u32x4 Bb[512];  // 8 KB  [fn 0..7][lane][16B]
  const int bid = blockIdx.x;
  const int ntile = bid & 31;
  const int mtile = bid >> 5;
  const int tid = threadIdx.x;
  const int lane = tid & 63;
  const int wid = tid >> 6;
  const int wm = wid & 1;
  const int wn = wid >> 1;
  const int m0 = mtile << 7;

  const f32x4 fz = {0.f, 0.f, 0.f, 0.f};
  f32x4 acc[4][4];
#pragma unroll
  for (int i = 0; i < 4; ++i)
#pragma unroll
    for (int j = 0; j < 4; ++j) acc[i][j] = fz;

  for (int kt = 0; kt < 16; ++kt) {
#pragma unroll
    for (int r = 0; r < 2; ++r) {
      const int c = tid + (r << 8);
      const int fl = c & 63;
      const int fmg = c >> 6;
      const int row = m0 + (fmg << 4) + (fl & 15);
      const int kc = (kt << 5) + ((fl >> 4) << 3);
      const float* s = x + (size_t)row * ED + kc;
      const float4 p0 = *(const float4*)s;
      const float4 p1 = *(const float4*)(s + 4);
      u32x4 v;
      v[0] = pk2(p0.x, p0.y);
      v[1] = pk2(p0.z, p0.w);
      v[2] = pk2(p1.x, p1.y);
      v[3] = pk2(p1.z, p1.w);
      Ab[c] = v;
    }
    {
      const u32x4* bsrc = wxp + (((size_t)(ntile << 4) + kt) << 9);
#pragma unroll
      for (int r = 0; r < 2; ++r) {
        const int cb = (wid << 6) + (r << 8);
        glds16((const void*)(bsrc + cb + lane), (void*)&Bb[cb]);
      }
    }
    __syncthreads();
    f16x8 afr[4], bfr[4];
#pragma unroll
    for (int f = 0; f < 4; ++f) afr[f] = __builtin_bit_cast(f16x8, Ab[((wm * 4 + f) << 6) + lane]);
#pragma unroll
    for (int f = 0; f < 4; ++f) bfr[f] = __builtin_bit_cast(f16x8, Bb[((wn * 4 + f) << 6) + lane]);
#pragma unroll
    for (int fm = 0; fm < 4; ++fm)
#pragma unroll
      for (int fn = 0; fn < 4; ++fn) acc[fm][fn] = mfma_f16(afr[fm], bfr[fn], acc[fm][fn]);
    __syncthreads();
  }

  char* const cb_ = outb;
  char* const hb_ = outb + OUT_HALF_BYTES;
  const int r0 = (lane >> 4) << 2;
#pragma unroll
  for (int fn = 0; fn < 4; ++fn) {
    const int np = (ntile << 7) + (wn << 6) + (fn << 4) + (lane & 15);
    const float bv = biasp[np];
    const int gg = (np >> 4) & 3;
    const int cg = np >> 6;
    const int jj = np & 15;
    char* const outHalf = (gg < 2) ? cb_ : hb_;
    const size_t coloff = (size_t)(cg << 6) + ((gg & 1) << 5) + (jj << 1);
#pragma unroll
    for (int fm = 0; fm < 4; ++fm) {
#pragma unroll
      for (int r = 0; r < 4; ++r) {
        const int m = m0 + (wm << 6) + (fm << 4) + r0 + r;
        *(u16*)(outHalf + (size_t)m * 4096 + coloff) = f2h(acc[fm][fn][r] + bv);
      }
    }
  }
}

// ---------------- persistent recurrence, self-announcing tagged h ----------------
// h value (row b, col jf) at generation g is stored as u32 (g<<16)|f16(h) in a
// ping-pong buffer hstg[g&1][b][jf]. Consumers poll their OWN fragment loads
// until every tag equals the expected generation: the detecting load IS the
// data load. No flags, no producer-side drain, no cross-block barriers.
// Tag EQUALITY makes poison (0xAAAA > 512) and graph replays safe (a replay's
// stale tags come from an identical previous call -> bit-identical values).

__global__ __launch_bounds__(256, 1) void lstm_rec(const float* __restrict__ c0,
                                                   const float* __restrict__ h0,
                                                   const u32x4* __restrict__ whp, char* outb,
                                                   u32* hstg) {
  __shared__ float zb[4][4][16][17];  // 17 KB partial z [kchunk][gate][row][col+pad]
  const int bid = blockIdx.x;
  const int mslab = bid & 3;   // batch slab (16 rows)
  const int cgp = bid >> 2;    // column group (16 h-cols x 4 gates)
  const int tid = threadIdx.x;
  const int lane = tid & 63;
  const int wid = tid >> 6;    // K-slice of 256
  const int b_loc = tid >> 4;
  const int j_loc = tid & 15;
  const int b = (mslab << 4) + b_loc;
  const int jf = (cgp << 4) + j_loc;

  // Wh slice -> VGPRs (4 gates x 8 kk x 16B/lane = 128 VGPR), loaded once
  f16x8 wreg[4][8];
  {
    const u32x4* wb = whp + (((size_t)(cgp * 4 + wid)) << 11);
#pragma unroll
    for (int g = 0; g < 4; ++g)
#pragma unroll
      for (int kk = 0; kk < 8; ++kk)
        wreg[g][kk] = __builtin_bit_cast(f16x8, wb[((g << 3) + kk) * 64 + lane]);
  }
  float creg = c0[(b << 10) + jf];
  // h0 tagged gen 0 into pp[0]
  stg_u32_cc(hstg + (b << 10) + jf, (u32)f2h(h0[(b << 10) + jf]));

  char* const cb_ = outb;
  char* const hb_ = outb + OUT_HALF_BYTES;

  // zx(0) prefetch (plain cached loads; producer kernel finished => visible)
  u32 xf16, xi16, xg16, xo16;
  {
    const size_t rowb = ((size_t)b) << 12;
    const char* crow = cb_ + rowb + (cgp << 6);
    const char* hrow = hb_ + rowb + (cgp << 6);
    xf16 = ldg_u16_plain(crow + (j_loc << 1));
    xi16 = ldg_u16_plain(crow + 32 + (j_loc << 1));
    xg16 = ldg_u16_plain(hrow + (j_loc << 1));
    xo16 = ldg_u16_plain(hrow + 32 + (j_loc << 1));
  }

  // per-lane consumer base (dwords): wave wid owns contiguous K-slice wid*256..+255
  const u32 aoff = (u32)((((mslab << 4) + (lane & 15)) << 10) + (wid << 8) + ((lane >> 4) << 3));

  const f32x4 fz = {0.f, 0.f, 0.f, 0.f};
#pragma unroll 1
  for (int t = 0; t < LT; ++t) {
    const u32* ab = hstg + (((u32)t & 1) << 16) + aoff;
    const u32 gtag = (u32)t << 16;
    u32x4 v[16];
    for (;;) {
#pragma unroll
      for (int kk = 0; kk < 8; ++kk) {
        v[2 * kk] = ldg16_cc(ab + (kk << 5));
        v[2 * kk + 1] = ldg16_cc(ab + (kk << 5) + 4);
      }
      waitv0();
      u32 acm = 0;
#pragma unroll
      for (int i = 0; i < 16; ++i)
        acm |= (v[i][0] ^ gtag) | (v[i][1] ^ gtag) | (v[i][2] ^ gtag) | (v[i][3] ^ gtag);
      if (__all(acm < 0x10000u)) break;
      __builtin_amdgcn_s_sleep(1);
    }

    f32x4 a0 = fz, a1 = fz, a2 = fz, a3 = fz;
#pragma unroll
    for (int kk = 0; kk < 8; ++kk) {
      const f16x8 av = unpk(v[2 * kk], v[2 * kk + 1]);
      a0 = mfma_f16(av, wreg[0][kk], a0);
      a1 = mfma_f16(av, wreg[1][kk], a1);
      a2 = mfma_f16(av, wreg[2][kk], a2);
      a3 = mfma_f16(av, wreg[3][kk], a3);
    }
    {
      const int rr = (lane >> 4) << 2;
      const int cc = lane & 15;
#pragma unroll
      for (int r = 0; r < 4; ++r) {
        zb[wid][0][rr + r][cc] = a0[r];
        zb[wid][1][rr + r][cc] = a1[r];
        zb[wid][2][rr + r][cc] = a2[r];
        zb[wid][3][rr + r][cc] = a3[r];
      }
    }
    __syncthreads();

    float zf = h2f((u16)xf16), zi = h2f((u16)xi16);
    float zg = h2f((u16)xg16), zo = h2f((u16)xo16);
#pragma unroll
    for (int w = 0; w < 4; ++w) {
      zf += zb[w][0][b_loc][j_loc];
      zi += zb[w][1][b_loc][j_loc];
      zg += zb[w][2][b_loc][j_loc];
      zo += zb[w][3][b_loc][j_loc];
    }
    __syncthreads();  // zb reads done before next iteration's writes

    const float fg = sigm(zf), ig = sigm(zi), gg = tanh_(zg), og = sigm(zo);
    creg = creg * fg + ig * gg;
    const float hv = og * tanh_(creg);

    // critical path: ONE tagged coherent store announces h(t+1)
    stg_u32_cc(hstg + ((((u32)(t + 1)) & 1) << 16) + (b << 10) + jf,
               (((u32)(t + 1)) << 16) | (u32)f2h(hv));

    // off-path: plain cached c/h output stores
    const size_t rowoff = ((size_t)((t << 6) + b)) << 12;
    *(float*)(cb_ + rowoff + ((size_t)jf << 2)) = creg;
    *(float*)(hb_ + rowoff + ((size_t)jf << 2)) = hv;

    // prefetch next step's zx under the tag propagation delay
    {
      const int tn = (t + 1 < LT) ? t + 1 : t;
      const size_t rown = ((size_t)((tn << 6) + b)) << 12;
      const char* crow = cb_ + rown + (cgp << 6);
      const char* hrow = hb_ + rown + (cgp << 6);
      xf16 = ldg_u16_plain(crow + (j_loc << 1));
      xi16 = ldg_u16_plain(crow + 32 + (j_loc << 1));
      xg16 = ldg_u16_plain(hrow + (j_loc << 1));
      xo16 = ldg_u16_plain(hrow + 32 + (j_loc << 1));
    }
  }
}

extern "C" void kernel_launch(void* const* d_in, const int* in_sizes, int n_in, void* d_out,
                              int out_size, void* d_ws, size_t ws_size, hipStream_t stream) {
  const float* x = (const float*)d_in[0];
  const float* c0 = (const float*)d_in[1];
  const float* h0 = (const float*)d_in[2];
  const float* Wf = (const float*)d_in[3];
  const float* bf = (const float*)d_in[4];
  const float* Wi = (const float*)d_in[5];
  const float* bi = (const float*)d_in[6];
  const float* Wg = (const float*)d_in[7];
  const float* bg = (const float*)d_in[8];
  const float* Wo = (const float*)d_in[9];
  const float* bo = (const float*)d_in[10];

  char* ws = (char*)d_ws;
  u32x4* wxp = (u32x4*)(ws + WXP_OFF);
  u32x4* whp = (u32x4*)(ws + WHP_OFF);
  float* bp = (float*)(ws + BIAS_OFF);
  u32* hstg = (u32*)(ws + HSTG_OFF);

  pack_wx<<<1024, 256, 0, stream>>>(Wf, Wi, Wg, Wo, wxp);
  pack_wh<<<2048, 256, 0, stream>>>(Wf, Wi, Wg, Wo, whp);
  pack_bias<<<16, 256, 0, stream>>>(bf, bi, bg, bo, bp);
  zx_gemm<<<8192, 256, 0, stream>>>(x, wxp, bp, (char*)d_out);
  lstm_rec<<<256, 256, 0, stream>>>(c0, h0, whp, (char*)d_out, hstg);
}

// Round 5
// 2773.228 us; speedup vs baseline: 1.0252x; 1.0252x over previous
//
#include <hip/hip_runtime.h>

typedef unsigned int u32;
typedef unsigned short u16;
using u32x4 = __attribute__((ext_vector_type(4))) u32;
using f16x8 = __attribute__((ext_vector_type(8))) _Float16;
using f32x4 = __attribute__((ext_vector_type(4))) float;

#define LT 512
#define BNB 64
#define ED 512
#define HD 1024
#define OUT_HALF_BYTES ((size_t)LT * BNB * HD * 4)  // 134217728 bytes per output tensor

// workspace layout (bytes)
#define WXP_OFF  ((size_t)0)                         // 4 MB  f16 fragment-packed Wx
#define WHP_OFF  ((size_t)(4u << 20))                // 8 MB  f16 fragment-packed Wh
#define BIAS_OFF ((size_t)(12u << 20))               // 16 KB packed bias (f32)
#define HSTG_OFF ((size_t)((12u << 20) + (16u << 10)))               // 512 KB tagged h ping-pong
#define FLAG_OFF ((size_t)((12u << 20) + (16u << 10) + (512u << 10)))  // 16 KB flags

__device__ __forceinline__ u16 f2h(float f) {
  _Float16 h = (_Float16)f;
  return __builtin_bit_cast(u16, h);
}
__device__ __forceinline__ float h2f(u16 s) {
  return (float)__builtin_bit_cast(_Float16, s);
}
__device__ __forceinline__ u32 pk2(float a, float b) {
  return (u32)f2h(a) | ((u32)f2h(b) << 16);
}
__device__ __forceinline__ void glds16(const void* g, void* l) {
  using GP = const __attribute__((address_space(1))) u32*;
  using SP = __attribute__((address_space(3))) u32*;
  __builtin_amdgcn_global_load_lds((GP)g, (SP)l, 16, 0, 0);
}
__device__ __forceinline__ f32x4 mfma_f16(f16x8 a, f16x8 b, f32x4 c) {
  return __builtin_amdgcn_mfma_f32_16x16x32_f16(a, b, c, 0, 0, 0);
}
__device__ __forceinline__ float sigm(float x) { return 1.0f / (1.0f + __expf(-x)); }
__device__ __forceinline__ float tanh_(float x) { return 2.0f / (1.0f + __expf(-2.0f * x)) - 1.0f; }

// ---- coherent (LLC-level, cross-XCD) ops: bypass L1+L2 with sc0 sc1 ----
__device__ __forceinline__ u32x4 ldg16_cc(const void* p) {
  u32x4 r;
  asm volatile("global_load_dwordx4 %0, %1, off sc0 sc1" : "=v"(r) : "v"(p) : "memory");
  return r;
}
__device__ __forceinline__ u32 ld_flag_cc(const void* p) {
  u32 r;
  asm volatile("global_load_dword %0, %1, off sc0 sc1\n\ts_waitcnt vmcnt(0)"
               : "=v"(r) : "v"(p) : "memory");
  return r;
}
__device__ __forceinline__ void stg_u32_cc(void* p, u32 v) {
  asm volatile("global_store_dword %0, %1, off sc0 sc1" ::"v"(p), "v"(v) : "memory");
}
__device__ __forceinline__ u32 ldg_u16_plain(const void* p) {
  u32 r;
  asm volatile("global_load_ushort %0, %1, off" : "=v"(r) : "v"(p) : "memory");
  return r;
}
__device__ __forceinline__ void waitv0() { asm volatile("s_waitcnt vmcnt(0)" ::: "memory"); }

// unpack 8 tagged dwords (low16 = f16 payload) into an f16x8 A-fragment
__device__ __forceinline__ f16x8 unpk(u32x4 lo, u32x4 hi) {
  u32x4 w;
  w[0] = (lo[0] & 0xFFFFu) | (lo[1] << 16);
  w[1] = (lo[2] & 0xFFFFu) | (lo[3] << 16);
  w[2] = (hi[0] & 0xFFFFu) | (hi[1] << 16);
  w[3] = (hi[2] & 0xFFFFu) | (hi[3] << 16);
  return __builtin_bit_cast(f16x8, w);
}

// ---------------- weight packing ----------------
// fragment convention for mfma_f32_16x16x32: lane l holds
//   A[row=l&15][k=8*(l>>4)+i]   B[k=8*(l>>4)+i][col=l&15]   (i=0..7, 16B per lane)
// gate-interleaved column index: n' = cg*64 + g*16 + j  (cg=0..63, g=f/i/g/o, j=0..15)

__global__ void pack_wx(const float* __restrict__ Wf, const float* __restrict__ Wi,
                        const float* __restrict__ Wg, const float* __restrict__ Wo,
                        u32x4* __restrict__ dst) {
  const int id = blockIdx.x * 256 + threadIdx.x;  // 262144 = 4096 frag-rows * 64 lanes
  const int lane = id & 63;
  const int row = id >> 6;           // ((ntile*16 + kt)*8 + fn)
  const int ntile = row >> 7;
  const int rem = row & 127;
  const int kt = rem >> 3;
  const int fn = rem & 7;
  const int np = (ntile << 7) + (fn << 4) + (lane & 15);
  const int g = (np >> 4) & 3;
  const int jfull = ((np >> 6) << 4) + (np & 15);
  const int k0 = (kt << 5) + ((lane >> 4) << 3);
  const float* W = (g == 0) ? Wf : (g == 1) ? Wi : (g == 2) ? Wg : Wo;
  const float* s = W + (size_t)k0 * HD + jfull;
  u16 h[8];
#pragma unroll
  for (int i = 0; i < 8; ++i) h[i] = f2h(s[(size_t)i * HD]);
  u32x4 v;
  v[0] = (u32)h[0] | ((u32)h[1] << 16);
  v[1] = (u32)h[2] | ((u32)h[3] << 16);
  v[2] = (u32)h[4] | ((u32)h[5] << 16);
  v[3] = (u32)h[6] | ((u32)h[7] << 16);
  dst[id] = v;
}

// Wh layout for 32-col blocks: frag_row = cq*256 + nt*32 + w*8 + kk
//   cq<32 (col-quarter: 32 h-cols = 128 n'), nt<8 (16-n' tile), w<4 (K-slice 256), kk<8
__global__ void pack_wh(const float* __restrict__ Wf, const float* __restrict__ Wi,
                        const float* __restrict__ Wg, const float* __restrict__ Wo,
                        u32x4* __restrict__ dst) {
  const int id = blockIdx.x * 256 + threadIdx.x;  // 524288 = 8192 frag-rows * 64 lanes
  const int lane = id & 63;
  const int row = id >> 6;
  const int kk = row & 7;
  const int w = (row >> 3) & 3;
  const int nt = (row >> 5) & 7;
  const int cq = row >> 8;
  const int np = (cq << 7) + (nt << 4) + (lane & 15);  // packed col n'
  const int g = (np >> 4) & 3;
  const int jfull = ((np >> 6) << 4) + (np & 15);
  const int k = ED + (w << 8) + (kk << 5) + ((lane >> 4) << 3);  // h-part rows of W
  const float* W = (g == 0) ? Wf : (g == 1) ? Wi : (g == 2) ? Wg : Wo;
  const float* s = W + (size_t)k * HD + jfull;
  u16 h[8];
#pragma unroll
  for (int i = 0; i < 8; ++i) h[i] = f2h(s[(size_t)i * HD]);
  u32x4 v;
  v[0] = (u32)h[0] | ((u32)h[1] << 16);
  v[1] = (u32)h[2] | ((u32)h[3] << 16);
  v[2] = (u32)h[4] | ((u32)h[5] << 16);
  v[3] = (u32)h[6] | ((u32)h[7] << 16);
  dst[id] = v;
}

__global__ void pack_bias_flags(const float* __restrict__ bf, const float* __restrict__ bi,
                                const float* __restrict__ bg, const float* __restrict__ bo,
                                float* __restrict__ dst, int* __restrict__ flags) {
  const int id = blockIdx.x * 256 + threadIdx.x;  // 4096
  const int g = (id >> 4) & 3;
  const int jfull = ((id >> 6) << 4) + (id & 15);
  const float* B = (g == 0) ? bf : (g == 1) ? bi : (g == 2) ? bg : bo;
  dst[id] = B[jfull];
  flags[id] = 0;  // reset flags every call (graph-replay safe; ordered before lstm_rec)
}

// ---------------- zx = X @ Wx + b  (written f16 into d_out's own bytes) ----------------
// zx element (m=t*64+b, n'=cg*64+g*16+j) lives at:
//   (g<2 ? c_half : h_half) + m*4096 + cg*64 + (g&1)*32 + j*2

__global__ __launch_bounds__(256) void zx_gemm(const float* __restrict__ x,
                                               const u32x4* __restrict__ wxp,
                                               const float* __restrict__ biasp,
                                               char* __restrict__ outb) {
  __shared__ u32x4 Ab[512];  // 8 KB  [fm 0..7][lane][16B]
  __shared__ u32x4 Bb[512];  // 8 KB  [fn 0..7][lane][16B]
  const int bid = blockIdx.x;
  const int ntile = bid & 31;
  const int mtile = bid >> 5;
  const int tid = threadIdx.x;
  const int lane = tid & 63;
  const int wid = tid >> 6;
  const int wm = wid & 1;
  const int wn = wid >> 1;
  const int m0 = mtile << 7;

  const f32x4 fz = {0.f, 0.f, 0.f, 0.f};
  f32x4 acc[4][4];
#pragma unroll
  for (int i = 0; i < 4; ++i)
#pragma unroll
    for (int j = 0; j < 4; ++j) acc[i][j] = fz;

  for (int kt = 0; kt < 16; ++kt) {
#pragma unroll
    for (int r = 0; r < 2; ++r) {
      const int c = tid + (r << 8);
      const int fl = c & 63;
      const int fmg = c >> 6;
      const int row = m0 + (fmg << 4) + (fl & 15);
      const int kc = (kt << 5) + ((fl >> 4) << 3);
      const float* s = x + (size_t)row * ED + kc;
      const float4 p0 = *(const float4*)s;
      const float4 p1 = *(const float4*)(s + 4);
      u32x4 v;
      v[0] = pk2(p0.x, p0.y);
      v[1] = pk2(p0.z, p0.w);
      v[2] = pk2(p1.x, p1.y);
      v[3] = pk2(p1.z, p1.w);
      Ab[c] = v;
    }
    {
      const u32x4* bsrc = wxp + (((size_t)(ntile << 4) + kt) << 9);
#pragma unroll
      for (int r = 0; r < 2; ++r) {
        const int cb = (wid << 6) + (r << 8);
        glds16((const void*)(bsrc + cb + lane), (void*)&Bb[cb]);
      }
    }
    __syncthreads();
    f16x8 afr[4], bfr[4];
#pragma unroll
    for (int f = 0; f < 4; ++f) afr[f] = __builtin_bit_cast(f16x8, Ab[((wm * 4 + f) << 6) + lane]);
#pragma unroll
    for (int f = 0; f < 4; ++f) bfr[f] = __builtin_bit_cast(f16x8, Bb[((wn * 4 + f) << 6) + lane]);
#pragma unroll
    for (int fm = 0; fm < 4; ++fm)
#pragma unroll
      for (int fn = 0; fn < 4; ++fn) acc[fm][fn] = mfma_f16(afr[fm], bfr[fn], acc[fm][fn]);
    __syncthreads();
  }

  char* const cb_ = outb;
  char* const hb_ = outb + OUT_HALF_BYTES;
  const int r0 = (lane >> 4) << 2;
#pragma unroll
  for (int fn = 0; fn < 4; ++fn) {
    const int np = (ntile << 7) + (wn << 6) + (fn << 4) + (lane & 15);
    const float bv = biasp[np];
    const int gg = (np >> 4) & 3;
    const int cg = np >> 6;
    const int jj = np & 15;
    char* const outHalf = (gg < 2) ? cb_ : hb_;
    const size_t coloff = (size_t)(cg << 6) + ((gg & 1) << 5) + (jj << 1);
#pragma unroll
    for (int fm = 0; fm < 4; ++fm) {
#pragma unroll
      for (int r = 0; r < 4; ++r) {
        const int m = m0 + (wm << 6) + (fm << 4) + r0 + r;
        *(u16*)(outHalf + (size_t)m * 4096 + coloff) = f2h(acc[fm][fn][r] + bv);
      }
    }
  }
}

// ---------------- persistent recurrence: flag-hint + tag-verify, drain-free ----------------
// Producer: tagged h stores ((gen<<16)|f16), __syncthreads (issue order only, NO vmcnt
// drain), tid0 stores flag=gen+1. Consumer: per-wave poll of the 32 group flags (hint),
// then ONE tagged fragment load verified by tag equality (guarantee; retry rare).
// Flags reset in-graph each call; tag equality makes poison/replay-stale data harmless.
// 128 blocks (4 slabs x 32 col-quarters); 1 block/CU by register budget -> full residency.

__global__ __launch_bounds__(256, 1) void lstm_rec(const float* __restrict__ c0,
                                                   const float* __restrict__ h0,
                                                   const u32x4* __restrict__ whp, char* outb,
                                                   u32* hstg, int* flags) {
  __shared__ float zb[4][8][16][17];  // 34.8 KB partial z [kslice][nt][row][col+pad]
  const int bid = blockIdx.x;
  const int mslab = bid & 3;   // batch slab (16 rows)
  const int cq = bid >> 2;     // col-quarter: 32 h-cols (128 n')
  const int tid = threadIdx.x;
  const int lane = tid & 63;
  const int wid = tid >> 6;    // K-slice of 256
  const int b_loc = tid >> 4;
  const int j_loc = tid & 15;
  const int b = (mslab << 4) + b_loc;
  const int col0 = (cq << 5) + j_loc;  // thread owns col0 and col0+16

  // Wh slice -> 256 regs/lane (8 nt x 8 kk x 16B); compiler offloads to AGPRs
  f16x8 wreg[8][8];
#pragma unroll
  for (int nt = 0; nt < 8; ++nt)
#pragma unroll
    for (int kk = 0; kk < 8; ++kk)
      wreg[nt][kk] = __builtin_bit_cast(
          f16x8, whp[((size_t)((cq << 8) + (nt << 5) + (wid << 3) + kk) << 6) + lane]);

  float creg0 = c0[(b << 10) + col0];
  float creg1 = c0[(b << 10) + col0 + 16];
  // h0 -> tagged gen 0 (tag bits = 0)
  stg_u32_cc(hstg + (b << 10) + col0, (u32)f2h(h0[(b << 10) + col0]));
  stg_u32_cc(hstg + (b << 10) + col0 + 16, (u32)f2h(h0[(b << 10) + col0 + 16]));

  char* const cb_ = outb;
  char* const hb_ = outb + OUT_HALF_BYTES;

  // zx(0) prefetch (plain cached; producer kernel finished => visible)
  u32 zx0[4], zx1[4];
  {
    const size_t rowb = ((size_t)b) << 12;
#pragma unroll
    for (int g = 0; g < 4; ++g) {
      const char* half = (g < 2) ? cb_ : hb_;
      zx0[g] = ldg_u16_plain(half + rowb + (cq << 7) + ((g & 1) << 5) + (j_loc << 1));
      zx1[g] = ldg_u16_plain(half + rowb + (cq << 7) + 64 + ((g & 1) << 5) + (j_loc << 1));
    }
  }
  __syncthreads();  // all h0 tagged stores issued
  if (tid == 0) stg_u32_cc(flags + (((mslab << 5) + cq) << 2), 1u);

  // per-lane fragment base (dwords): row = mslab*16+(lane&15), k = wid*256+(lane>>4)*8
  const u32 aoff = (u32)((((mslab << 4) + (lane & 15)) << 10) + (wid << 8) + ((lane >> 4) << 3));
  const int* const pf = flags + (((mslab << 5) + (lane & 31)) << 2);

  const f32x4 fz = {0.f, 0.f, 0.f, 0.f};
#pragma unroll 1
  for (int t = 0; t < LT; ++t) {
    // flag gate (latency hint only)
    while ((int)ld_flag_cc(pf) < t + 1) {}

    // tagged fragment load + verify (the guarantee)
    const u32* ab = hstg + (((u32)t & 1) << 16) + aoff;
    const u32 gtag = (u32)t << 16;
    u32x4 v[16];
    for (;;) {
#pragma unroll
      for (int kk = 0; kk < 8; ++kk) {
        v[2 * kk] = ldg16_cc(ab + (kk << 5));
        v[2 * kk + 1] = ldg16_cc(ab + (kk << 5) + 4);
      }
      waitv0();
      u32 acm = 0;
#pragma unroll
      for (int i = 0; i < 16; ++i)
        acm |= (v[i][0] ^ gtag) | (v[i][1] ^ gtag) | (v[i][2] ^ gtag) | (v[i][3] ^ gtag);
      if (__all(acm < 0x10000u)) break;
    }

    f32x4 acc[8];
#pragma unroll
    for (int nt = 0; nt < 8; ++nt) acc[nt] = fz;
#pragma unroll
    for (int kk = 0; kk < 8; ++kk) {
      const f16x8 av = unpk(v[2 * kk], v[2 * kk + 1]);
#pragma unroll
      for (int nt = 0; nt < 8; ++nt) acc[nt] = mfma_f16(av, wreg[nt][kk], acc[nt]);
    }
    {
      const int rr = (lane >> 4) << 2;
      const int cc = lane & 15;
#pragma unroll
      for (int nt = 0; nt < 8; ++nt)
#pragma unroll
        for (int r = 0; r < 4; ++r) zb[wid][nt][rr + r][cc] = acc[nt][r];
    }
    __syncthreads();  // S2: partials visible

    float hv0, hv1;
    {
      float z[4];
#pragma unroll
      for (int g = 0; g < 4; ++g) {
        float s = h2f((u16)zx0[g]);
#pragma unroll
        for (int w = 0; w < 4; ++w) s += zb[w][g][b_loc][j_loc];
        z[g] = s;
      }
      const float fg = sigm(z[0]), ig = sigm(z[1]), gg = tanh_(z[2]), og = sigm(z[3]);
      creg0 = creg0 * fg + ig * gg;
      hv0 = og * tanh_(creg0);
    }
    {
      float z[4];
#pragma unroll
      for (int g = 0; g < 4; ++g) {
        float s = h2f((u16)zx1[g]);
#pragma unroll
        for (int w = 0; w < 4; ++w) s += zb[w][4 + g][b_loc][j_loc];
        z[g] = s;
      }
      const float fg = sigm(z[0]), ig = sigm(z[1]), gg = tanh_(z[2]), og = sigm(z[3]);
      creg1 = creg1 * fg + ig * gg;
      hv1 = og * tanh_(creg1);
    }

    // critical path: tagged stores announce h(t+1); no drain
    const u32 ntag = ((u32)(t + 1)) << 16;
    u32* hdst = hstg + ((((u32)(t + 1)) & 1) << 16) + (b << 10) + col0;
    stg_u32_cc(hdst, ntag | (u32)f2h(hv0));
    stg_u32_cc(hdst + 16, ntag | (u32)f2h(hv1));
    __syncthreads();  // S3: all tagged stores issued; also zb read/write separation
    if (tid == 0) stg_u32_cc(flags + (((mslab << 5) + cq) << 2), (u32)(t + 2));

    // off-path: plain cached c/h output stores
    const size_t rowoff = ((size_t)((t << 6) + b)) << 12;
    *(float*)(cb_ + rowoff + ((size_t)col0 << 2)) = creg0;
    *(float*)(cb_ + rowoff + ((size_t)(col0 + 16) << 2)) = creg1;
    *(float*)(hb_ + rowoff + ((size_t)col0 << 2)) = hv0;
    *(float*)(hb_ + rowoff + ((size_t)(col0 + 16) << 2)) = hv1;

    // zx prefetch t+1 under the flag propagation delay
    {
      const int tn = (t + 1 < LT) ? t + 1 : t;
      const size_t rown = ((size_t)((tn << 6) + b)) << 12;
#pragma unroll
      for (int g = 0; g < 4; ++g) {
        const char* half = (g < 2) ? cb_ : hb_;
        zx0[g] = ldg_u16_plain(half + rown + (cq << 7) + ((g & 1) << 5) + (j_loc << 1));
        zx1[g] = ldg_u16_plain(half + rown + (cq << 7) + 64 + ((g & 1) << 5) + (j_loc << 1));
      }
    }
  }
}

extern "C" void kernel_launch(void* const* d_in, const int* in_sizes, int n_in, void* d_out,
                              int out_size, void* d_ws, size_t ws_size, hipStream_t stream) {
  const float* x = (const float*)d_in[0];
  const float* c0 = (const float*)d_in[1];
  const float* h0 = (const float*)d_in[2];
  const float* Wf = (const float*)d_in[3];
  const float* bf = (const float*)d_in[4];
  const float* Wi = (const float*)d_in[5];
  const float* bi = (const float*)d_in[6];
  const float* Wg = (const float*)d_in[7];
  const float* bg = (const float*)d_in[8];
  const float* Wo = (const float*)d_in[9];
  const float* bo = (const float*)d_in[10];

  char* ws = (char*)d_ws;
  u32x4* wxp = (u32x4*)(ws + WXP_OFF);
  u32x4* whp = (u32x4*)(ws + WHP_OFF);
  float* bp = (float*)(ws + BIAS_OFF);
  u32* hstg = (u32*)(ws + HSTG_OFF);
  int* flags = (int*)(ws + FLAG_OFF);

  pack_wx<<<1024, 256, 0, stream>>>(Wf, Wi, Wg, Wo, wxp);
  pack_wh<<<2048, 256, 0, stream>>>(Wf, Wi, Wg, Wo, whp);
  pack_bias_flags<<<16, 256, 0, stream>>>(bf, bi, bg, bo, bp, flags);
  zx_gemm<<<8192, 256, 0, stream>>>(x, wxp, bp, (char*)d_out);
  lstm_rec<<<128, 256, 0, stream>>>(c0, h0, whp, (char*)d_out, hstg, flags);
}

// Round 7
// 2401.360 us; speedup vs baseline: 1.1839x; 1.1549x over previous
//
#include <hip/hip_runtime.h>

typedef unsigned int u32;
typedef unsigned short u16;
using u32x4 = __attribute__((ext_vector_type(4))) u32;
using f16x8 = __attribute__((ext_vector_type(8))) _Float16;
using f32x4 = __attribute__((ext_vector_type(4))) float;

#define LT 512
#define BNB 64
#define ED 512
#define HD 1024
#define OUT_HALF_BYTES ((size_t)LT * BNB * HD * 4)  // 134217728 bytes per output tensor

// workspace layout (bytes)
#define WXP_OFF  ((size_t)0)                         // 4 MB  f16 fragment-packed Wx
#define WHP_OFF  ((size_t)(4u << 20))                // 8 MB  f16 fragment-packed Wh
#define BIAS_OFF ((size_t)(12u << 20))               // 16 KB packed bias (f32)
#define HSTG_OFF ((size_t)((12u << 20) + (16u << 10)))               // 256 KB h ping-pong (u16)
#define FLAG_OFF ((size_t)((12u << 20) + (16u << 10) + (512u << 10)))  // 32 KB flags (128B-spaced)

__device__ __forceinline__ u16 f2h(float f) {
  _Float16 h = (_Float16)f;
  return __builtin_bit_cast(u16, h);
}
__device__ __forceinline__ float h2f(u16 s) {
  return (float)__builtin_bit_cast(_Float16, s);
}
__device__ __forceinline__ u32 pk2(float a, float b) {
  return (u32)f2h(a) | ((u32)f2h(b) << 16);
}
__device__ __forceinline__ void glds16(const void* g, void* l) {
  using GP = const __attribute__((address_space(1))) u32*;
  using SP = __attribute__((address_space(3))) u32*;
  __builtin_amdgcn_global_load_lds((GP)g, (SP)l, 16, 0, 0);
}
__device__ __forceinline__ f32x4 mfma_f16(f16x8 a, f16x8 b, f32x4 c) {
  return __builtin_amdgcn_mfma_f32_16x16x32_f16(a, b, c, 0, 0, 0);
}
__device__ __forceinline__ float sigm(float x) { return 1.0f / (1.0f + __expf(-x)); }
__device__ __forceinline__ float tanh_(float x) { return 2.0f / (1.0f + __expf(-2.0f * x)) - 1.0f; }

// ---- coherent (LLC-level, cross-XCD) ops: bypass L1+L2 with sc0 sc1 ----
__device__ __forceinline__ u32x4 ldg16_cc(const void* p) {
  u32x4 r;
  asm volatile("global_load_dwordx4 %0, %1, off sc0 sc1" : "=v"(r) : "v"(p) : "memory");
  return r;
}
__device__ __forceinline__ u32 ld_flag_cc(const void* p) {  // embedded wait
  u32 r;
  asm volatile("global_load_dword %0, %1, off sc0 sc1\n\ts_waitcnt vmcnt(0)"
               : "=v"(r) : "v"(p) : "memory");
  return r;
}
__device__ __forceinline__ void st_u16_cc(void* p, u32 v) {
  asm volatile("global_store_short %0, %1, off sc0 sc1" ::"v"(p), "v"(v) : "memory");
}
__device__ __forceinline__ void stg_u32_cc(void* p, u32 v) {
  asm volatile("global_store_dword %0, %1, off sc0 sc1" ::"v"(p), "v"(v) : "memory");
}
__device__ __forceinline__ u32 ldg_u16_plain(const void* p) {
  u32 r;
  asm volatile("global_load_ushort %0, %1, off" : "=v"(r) : "v"(p) : "memory");
  return r;
}
__device__ __forceinline__ void waitv0() { asm volatile("s_waitcnt vmcnt(0)" ::: "memory"); }

// ---------------- weight packing ----------------
// fragment convention for mfma_f32_16x16x32: lane l holds
//   A[row=l&15][k=8*(l>>4)+i]   B[k=8*(l>>4)+i][col=l&15]   (i=0..7, 16B per lane)
// gate-interleaved column index: n' = cg*64 + g*16 + j  (cg=0..63, g=f/i/g/o, j=0..15)

__global__ void pack_wx(const float* __restrict__ Wf, const float* __restrict__ Wi,
                        const float* __restrict__ Wg, const float* __restrict__ Wo,
                        u32x4* __restrict__ dst) {
  const int id = blockIdx.x * 256 + threadIdx.x;  // 262144 = 4096 frag-rows * 64 lanes
  const int lane = id & 63;
  const int row = id >> 6;           // ((ntile*16 + kt)*8 + fn)
  const int ntile = row >> 7;
  const int rem = row & 127;
  const int kt = rem >> 3;
  const int fn = rem & 7;
  const int np = (ntile << 7) + (fn << 4) + (lane & 15);
  const int g = (np >> 4) & 3;
  const int jfull = ((np >> 6) << 4) + (np & 15);
  const int k0 = (kt << 5) + ((lane >> 4) << 3);
  const float* W = (g == 0) ? Wf : (g == 1) ? Wi : (g == 2) ? Wg : Wo;
  const float* s = W + (size_t)k0 * HD + jfull;
  u16 h[8];
#pragma unroll
  for (int i = 0; i < 8; ++i) h[i] = f2h(s[(size_t)i * HD]);
  u32x4 v;
  v[0] = (u32)h[0] | ((u32)h[1] << 16);
  v[1] = (u32)h[2] | ((u32)h[3] << 16);
  v[2] = (u32)h[4] | ((u32)h[5] << 16);
  v[3] = (u32)h[6] | ((u32)h[7] << 16);
  dst[id] = v;
}

// Wh layout for 32-col blocks (r5-proven): frag_row = cq*256 + nt*32 + w*8 + kk
//   cq<32 (col-quarter: 32 h-cols = 128 n'), nt<8 (16-n' tile), w<4 (K-slice 256), kk<8
__global__ void pack_wh(const float* __restrict__ Wf, const float* __restrict__ Wi,
                        const float* __restrict__ Wg, const float* __restrict__ Wo,
                        u32x4* __restrict__ dst) {
  const int id = blockIdx.x * 256 + threadIdx.x;  // 524288 = 8192 frag-rows * 64 lanes
  const int lane = id & 63;
  const int row = id >> 6;
  const int kk = row & 7;
  const int w = (row >> 3) & 3;
  const int nt = (row >> 5) & 7;
  const int cq = row >> 8;
  const int np = (cq << 7) + (nt << 4) + (lane & 15);  // packed col n'
  const int g = (np >> 4) & 3;
  const int jfull = ((np >> 6) << 4) + (np & 15);
  const int k = ED + (w << 8) + (kk << 5) + ((lane >> 4) << 3);  // h-part rows of W
  const float* W = (g == 0) ? Wf : (g == 1) ? Wi : (g == 2) ? Wg : Wo;
  const float* s = W + (size_t)k * HD + jfull;
  u16 h[8];
#pragma unroll
  for (int i = 0; i < 8; ++i) h[i] = f2h(s[(size_t)i * HD]);
  u32x4 v;
  v[0] = (u32)h[0] | ((u32)h[1] << 16);
  v[1] = (u32)h[2] | ((u32)h[3] << 16);
  v[2] = (u32)h[4] | ((u32)h[5] << 16);
  v[3] = (u32)h[6] | ((u32)h[7] << 16);
  dst[id] = v;
}

__global__ void pack_bias_flags(const float* __restrict__ bf, const float* __restrict__ bi,
                                const float* __restrict__ bg, const float* __restrict__ bo,
                                float* __restrict__ dst, int* __restrict__ flags) {
  const int id = blockIdx.x * 256 + threadIdx.x;  // 8192
  if (id < 4096) {
    const int g = (id >> 4) & 3;
    const int jfull = ((id >> 6) << 4) + (id & 15);
    const float* B = (g == 0) ? bf : (g == 1) ? bi : (g == 2) ? bg : bo;
    dst[id] = B[jfull];
  }
  flags[id] = 0;  // reset 32 KB padded flags every call (graph-replay safe)
}

// ---------------- zx = X @ Wx + b  (written f16 into d_out's own bytes) ----------------
// zx element (m=t*64+b, n'=cg*64+g*16+j) lives at:
//   (g<2 ? c_half : h_half) + m*4096 + cg*64 + (g&1)*32 + j*2

__global__ __launch_bounds__(256) void zx_gemm(const float* __restrict__ x,
                                               const u32x4* __restrict__ wxp,
                                               const float* __restrict__ biasp,
                                               char* __restrict__ outb) {
  __shared__ u32x4 Ab[512];  // 8 KB  [fm 0..7][lane][16B]
  __shared__ u32x4 Bb[512];  // 8 KB  [fn 0..7][lane][16B]
  const int bid = blockIdx.x;
  const int ntile = bid & 31;
  const int mtile = bid >> 5;
  const int tid = threadIdx.x;
  const int lane = tid & 63;
  const int wid = tid >> 6;
  const int wm = wid & 1;
  const int wn = wid >> 1;
  const int m0 = mtile << 7;

  const f32x4 fz = {0.f, 0.f, 0.f, 0.f};
  f32x4 acc[4][4];
#pragma unroll
  for (int i = 0; i < 4; ++i)
#pragma unroll
    for (int j = 0; j < 4; ++j) acc[i][j] = fz;

  for (int kt = 0; kt < 16; ++kt) {
#pragma unroll
    for (int r = 0; r < 2; ++r) {
      const int c = tid + (r << 8);
      const int fl = c & 63;
      const int fmg = c >> 6;
      const int row = m0 + (fmg << 4) + (fl & 15);
      const int kc = (kt << 5) + ((fl >> 4) << 3);
      const float* s = x + (size_t)row * ED + kc;
      const float4 p0 = *(const float4*)s;
      const float4 p1 = *(const float4*)(s + 4);
      u32x4 v;
      v[0] = pk2(p0.x, p0.y);
      v[1] = pk2(p0.z, p0.w);
      v[2] = pk2(p1.x, p1.y);
      v[3] = pk2(p1.z, p1.w);
      Ab[c] = v;
    }
    {
      const u32x4* bsrc = wxp + (((size_t)(ntile << 4) + kt) << 9);
#pragma unroll
      for (int r = 0; r < 2; ++r) {
        const int cb = (wid << 6) + (r << 8);
        glds16((const void*)(bsrc + cb + lane), (void*)&Bb[cb]);
      }
    }
    __syncthreads();
    f16x8 afr[4], bfr[4];
#pragma unroll
    for (int f = 0; f < 4; ++f) afr[f] = __builtin_bit_cast(f16x8, Ab[((wm * 4 + f) << 6) + lane]);
#pragma unroll
    for (int f = 0; f < 4; ++f) bfr[f] = __builtin_bit_cast(f16x8, Bb[((wn * 4 + f) << 6) + lane]);
#pragma unroll
    for (int fm = 0; fm < 4; ++fm)
#pragma unroll
      for (int fn = 0; fn < 4; ++fn) acc[fm][fn] = mfma_f16(afr[fm], bfr[fn], acc[fm][fn]);
    __syncthreads();
  }

  char* const cb_ = outb;
  char* const hb_ = outb + OUT_HALF_BYTES;
  const int r0 = (lane >> 4) << 2;
#pragma unroll
  for (int fn = 0; fn < 4; ++fn) {
    const int np = (ntile << 7) + (wn << 6) + (fn << 4) + (lane & 15);
    const float bv = biasp[np];
    const int gg = (np >> 4) & 3;
    const int cg = np >> 6;
    const int jj = np & 15;
    char* const outHalf = (gg < 2) ? cb_ : hb_;
    const size_t coloff = (size_t)(cg << 6) + ((gg & 1) << 5) + (jj << 1);
#pragma unroll
    for (int fm = 0; fm < 4; ++fm) {
#pragma unroll
      for (int r = 0; r < 4; ++r) {
        const int m = m0 + (wm << 6) + (fm << 4) + r0 + r;
        *(u16*)(outHalf + (size_t)m * 4096 + coloff) = f2h(acc[fm][fn][r] + bv);
      }
    }
  }
}

// ---------------- persistent recurrence: r2 protocol @ r5 geometry ----------------
// Producer: [plain c/h stores + zx prefetch issued first] -> h stores (sc0 sc1 u16) ->
// vmcnt(0) drain -> barrier -> tid0 flag store (128B-spaced). Consumer: EVERY wave polls
// the 32 producer flags of its slab (lanes mod 32, flag load embedded vmcnt), THEN issues
// its data loads (chained: provably fresh). 128 blocks = 4 slabs x 32 col-groups(32 cols).

__global__ __launch_bounds__(256, 1) void lstm_rec(const float* __restrict__ c0,
                                                   const float* __restrict__ h0,
                                                   const u32x4* __restrict__ whp, char* outb,
                                                   u16* hstage, int* flags) {
  __shared__ float zb[4][8][16][17];  // 34.8 KB partial z [kslice][nt][row][col+pad]
  const int bid = blockIdx.x;
  const int mslab = bid & 3;   // batch slab (16 rows)
  const int cq = bid >> 2;     // col-quarter: 32 h-cols (128 n')
  const int tid = threadIdx.x;
  const int lane = tid & 63;
  const int wid = tid >> 6;    // K-slice of 256
  const int b_loc = tid >> 4;
  const int j_loc = tid & 15;
  const int b = (mslab << 4) + b_loc;
  const int col0 = (cq << 5) + j_loc;  // thread owns col0 and col0+16

  // Wh slice -> 256 regs/lane (8 nt x 8 kk x 16B); unified VGPR/AGPR file at 1 wave/SIMD
  f16x8 wreg[8][8];
#pragma unroll
  for (int nt = 0; nt < 8; ++nt)
#pragma unroll
    for (int kk = 0; kk < 8; ++kk)
      wreg[nt][kk] = __builtin_bit_cast(
          f16x8, whp[((size_t)((cq << 8) + (nt << 5) + (wid << 3) + kk) << 6) + lane]);

  float creg0 = c0[(b << 10) + col0];
  float creg1 = c0[(b << 10) + col0 + 16];

  char* const cb_ = outb;
  char* const hb_ = outb + OUT_HALF_BYTES;

  // zx(0) prefetch (plain cached; producer kernel finished => visible)
  u32 zx0[4], zx1[4];
  {
    const size_t rowb = ((size_t)b) << 12;
#pragma unroll
    for (int g = 0; g < 4; ++g) {
      const char* half = (g < 2) ? cb_ : hb_;
      zx0[g] = ldg_u16_plain(half + rowb + (cq << 7) + ((g & 1) << 5) + (j_loc << 1));
      zx1[g] = ldg_u16_plain(half + rowb + (cq << 7) + 64 + ((g & 1) << 5) + (j_loc << 1));
    }
  }
  // h0 -> exchange buffer (gen 0 slot), drain, barrier, flag gen 1
  st_u16_cc(hstage + (b << 10) + col0, (u32)f2h(h0[(b << 10) + col0]));
  st_u16_cc(hstage + (b << 10) + col0 + 16, (u32)f2h(h0[(b << 10) + col0 + 16]));
  waitv0();
  __syncthreads();
  if (tid == 0) stg_u32_cc(flags + (((mslab << 5) + cq) << 5), 1u);

  // per-lane fragment base (u16 units): row = mslab*16+(lane&15), k = wid*256+(lane>>4)*8
  const u32 aoff = (u32)((((mslab << 4) + (lane & 15)) << 10) + (wid << 8) + ((lane >> 4) << 3));
  const int* const pf = flags + (((mslab << 5) + (lane & 31)) << 5);

  const f32x4 fz = {0.f, 0.f, 0.f, 0.f};
#pragma unroll 1
  for (int t = 0; t < LT; ++t) {
    // ---- per-wave flag poll (hint AND guarantee: data loads are chained after) ----
    u32 fl;
    do {
      fl = (u32)ld_flag_cc(pf);
    } while (!__all((int)(fl >= (u32)(t + 1))));

    // chained data load: provably fresh (issued after flag observation)
    const u16* ab = hstage + (((u32)t & 1) << 16) + aoff;
    u32x4 v[8];
#pragma unroll
    for (int kk = 0; kk < 8; ++kk) v[kk] = ldg16_cc(ab + (kk << 5));
    waitv0();
    __builtin_amdgcn_sched_barrier(0);

    f32x4 acc[8];
#pragma unroll
    for (int nt = 0; nt < 8; ++nt) acc[nt] = fz;
#pragma unroll
    for (int kk = 0; kk < 8; ++kk) {
      const f16x8 av = __builtin_bit_cast(f16x8, v[kk]);
#pragma unroll
      for (int nt = 0; nt < 8; ++nt) acc[nt] = mfma_f16(av, wreg[nt][kk], acc[nt]);
    }
    {
      const int rr = (lane >> 4) << 2;
      const int cc = lane & 15;
#pragma unroll
      for (int nt = 0; nt < 8; ++nt)
#pragma unroll
        for (int r = 0; r < 4; ++r) zb[wid][nt][rr + r][cc] = acc[nt][r];
    }
    __syncthreads();  // S2: partials visible

    float hv0, hv1;
    {
      float z[4];
#pragma unroll
      for (int g = 0; g < 4; ++g) {
        float s = h2f((u16)zx0[g]);
#pragma unroll
        for (int w = 0; w < 4; ++w) s += zb[w][g][b_loc][j_loc];
        z[g] = s;
      }
      const float fg = sigm(z[0]), ig = sigm(z[1]), gg = tanh_(z[2]), og = sigm(z[3]);
      creg0 = creg0 * fg + ig * gg;
      hv0 = og * tanh_(creg0);
    }
    {
      float z[4];
#pragma unroll
      for (int g = 0; g < 4; ++g) {
        float s = h2f((u16)zx1[g]);
#pragma unroll
        for (int w = 0; w < 4; ++w) s += zb[w][4 + g][b_loc][j_loc];
        z[g] = s;
      }
      const float fg = sigm(z[0]), ig = sigm(z[1]), gg = tanh_(z[2]), og = sigm(z[3]);
      creg1 = creg1 * fg + ig * gg;
      hv1 = og * tanh_(creg1);
    }

    // off-path issues FIRST so the single drain covers them (keeps polls clean)
    const size_t rowoff = ((size_t)((t << 6) + b)) << 12;
    *(float*)(cb_ + rowoff + ((size_t)col0 << 2)) = creg0;
    *(float*)(cb_ + rowoff + ((size_t)(col0 + 16) << 2)) = creg1;
    *(float*)(hb_ + rowoff + ((size_t)col0 << 2)) = hv0;
    *(float*)(hb_ + rowoff + ((size_t)(col0 + 16) << 2)) = hv1;
    {
      const int tn = (t + 1 < LT) ? t + 1 : t;
      const size_t rown = ((size_t)((tn << 6) + b)) << 12;
#pragma unroll
      for (int g = 0; g < 4; ++g) {
        const char* half = (g < 2) ? cb_ : hb_;
        zx0[g] = ldg_u16_plain(half + rown + (cq << 7) + ((g & 1) << 5) + (j_loc << 1));
        zx1[g] = ldg_u16_plain(half + rown + (cq << 7) + 64 + ((g & 1) << 5) + (j_loc << 1));
      }
    }

    // critical path: h(t+1) -> LLC, drain, barrier, flag
    u16* hdst = hstage + ((((u32)(t + 1)) & 1) << 16) + (b << 10) + col0;
    st_u16_cc(hdst, (u32)f2h(hv0));
    st_u16_cc(hdst + 16, (u32)f2h(hv1));
    waitv0();
    __syncthreads();  // S3: all waves drained; also zb read/write separation
    if (tid == 0) stg_u32_cc(flags + (((mslab << 5) + cq) << 5), (u32)(t + 2));
  }
}

extern "C" void kernel_launch(void* const* d_in, const int* in_sizes, int n_in, void* d_out,
                              int out_size, void* d_ws, size_t ws_size, hipStream_t stream) {
  const float* x = (const float*)d_in[0];
  const float* c0 = (const float*)d_in[1];
  const float* h0 = (const float*)d_in[2];
  const float* Wf = (const float*)d_in[3];
  const float* bf = (const float*)d_in[4];
  const float* Wi = (const float*)d_in[5];
  const float* bi = (const float*)d_in[6];
  const float* Wg = (const float*)d_in[7];
  const float* bg = (const float*)d_in[8];
  const float* Wo = (const float*)d_in[9];
  const float* bo = (const float*)d_in[10];

  char* ws = (char*)d_ws;
  u32x4* wxp = (u32x4*)(ws + WXP_OFF);
  u32x4* whp = (u32x4*)(ws + WHP_OFF);
  float* bp = (float*)(ws + BIAS_OFF);
  u16* hstage = (u16*)(ws + HSTG_OFF);
  int* flags = (int*)(ws + FLAG_OFF);

  pack_wx<<<1024, 256, 0, stream>>>(Wf, Wi, Wg, Wo, wxp);
  pack_wh<<<2048, 256, 0, stream>>>(Wf, Wi, Wg, Wo, whp);
  pack_bias_flags<<<32, 256, 0, stream>>>(bf, bi, bg, bo, bp, flags);
  zx_gemm<<<8192, 256, 0, stream>>>(x, wxp, bp, (char*)d_out);
  lstm_rec<<<128, 256, 0, stream>>>(c0, h0, whp, (char*)d_out, hstage, flags);
}